// Round 3
// baseline (787.643 us; speedup 1.0000x reference)
//
#include <hip/hip_runtime.h>

#define NN 50000
#define NE 1600000
#define DD 64
#define NB 196                          // ceil(NN / 256) row-buckets
#define EPB 4096                        // edges per sort block
#define NBLK ((NE + EPB - 1) / EPB)     // 391

// ---------- K1: global bucket histogram (LDS-aggregated) ----------
__global__ __launch_bounds__(1024) void hist_buckets(
    const int* __restrict__ erow, int* __restrict__ gcnt)
{
    __shared__ int h[256];
    int tid = threadIdx.x;
    if (tid < 256) h[tid] = 0;
    __syncthreads();
    int base = blockIdx.x * EPB;
    #pragma unroll
    for (int i = 0; i < 4; ++i) {
        int e = base + i * 1024 + tid;
        if (e < NE) atomicAdd(&h[erow[e] >> 8], 1);
    }
    __syncthreads();
    if (tid < 256) { int c = h[tid]; if (c) atomicAdd(&gcnt[tid], c); }
}

// ---------- K2: exclusive scan of 256 bucket counts, one wave ----------
__global__ __launch_bounds__(64) void scan_buckets(int* __restrict__ gc)
{
    int lane = threadIdx.x;
    int c0 = gc[lane*4+0], c1 = gc[lane*4+1], c2 = gc[lane*4+2], c3 = gc[lane*4+3];
    int s = c0 + c1 + c2 + c3;
    int v = s;
    #pragma unroll
    for (int off = 1; off < 64; off <<= 1) {
        int u = __shfl_up(v, off, 64);
        if (lane >= off) v += u;
    }
    int run = v - s;                    // exclusive prefix of this lane's 4 bins
    gc[lane*4+0] = run;
    gc[lane*4+1] = run + c0;
    gc[lane*4+2] = run + c0 + c1;
    gc[lane*4+3] = run + c0 + c1 + c2;
}

// ---------- K3: block-local counting sort + contiguous-run copy-out ----------
// After this kernel gcur[b] == end offset of bucket b (start = gcur[b-1]).
__global__ __launch_bounds__(1024) void bucket_scatter(
    const int* __restrict__ erow, const int* __restrict__ ecol,
    const float* __restrict__ evals,
    int* __restrict__ gcur, int2* __restrict__ bkt)
{
    __shared__ int hist[256];
    __shared__ int lstart[256];
    __shared__ int gbase[256];
    __shared__ int2 data[EPB];          // 32 KB
    __shared__ unsigned char sbkt[EPB]; // 4 KB

    int tid = threadIdx.x;
    if (tid < 256) hist[tid] = 0;
    __syncthreads();

    int base = blockIdx.x * EPB;
    int r[4], c[4], bk[4]; float v[4];
    #pragma unroll
    for (int i = 0; i < 4; ++i) {
        int e = base + i * 1024 + tid;
        if (e < NE) {
            r[i] = erow[e]; c[i] = ecol[e]; v[i] = evals[e];
            bk[i] = r[i] >> 8;
            atomicAdd(&hist[bk[i]], 1);
        } else bk[i] = -1;
    }
    __syncthreads();

    if (tid < 64) {                     // wave 0: exclusive scan of 256 bins
        int lane = tid;
        int c0 = hist[lane*4], c1 = hist[lane*4+1],
            c2 = hist[lane*4+2], c3 = hist[lane*4+3];
        int s = c0 + c1 + c2 + c3, vv = s;
        #pragma unroll
        for (int off = 1; off < 64; off <<= 1) {
            int u = __shfl_up(vv, off, 64);
            if (lane >= off) vv += u;
        }
        int run = vv - s;
        lstart[lane*4]   = run;
        lstart[lane*4+1] = run + c0;
        lstart[lane*4+2] = run + c0 + c1;
        lstart[lane*4+3] = run + c0 + c1 + c2;
    }
    __syncthreads();

    if (tid < 256) {                    // reserve global runs; repurpose hist as cursor
        int cnt = hist[tid];
        gbase[tid] = cnt ? atomicAdd(&gcur[tid], cnt) : 0;
        hist[tid] = lstart[tid];
    }
    __syncthreads();

    #pragma unroll
    for (int i = 0; i < 4; ++i) {       // scatter into LDS, bucket-grouped
        if (bk[i] >= 0) {
            int p = atomicAdd(&hist[bk[i]], 1);
            data[p] = make_int2(((r[i] & 255) << 16) | c[i], __float_as_int(v[i]));
            sbkt[p] = (unsigned char)bk[i];
        }
    }
    __syncthreads();

    int total = NE - base; if (total > EPB) total = EPB;
    #pragma unroll
    for (int i = 0; i < 4; ++i) {       // coalesced copy-out of contiguous runs
        int slot = i * 1024 + tid;
        if (slot < total) {
            int bb = sbkt[slot];
            bkt[gbase[bb] + slot - lstart[bb]] = data[slot];
        }
    }
}

// ---------- K4: fused bucket SpMM (LDS tile) + h0 mix + GEMM ----------
// out = ((1-s)*A@x + s*h0) @ (theta*W + (1-theta)*I), one block per 256 rows
__global__ __launch_bounds__(1024) void fused_spmm_gemm(
    const float* __restrict__ x,  const float* __restrict__ h0,
    const float* __restrict__ W,  const float* __restrict__ lamda,
    const float* __restrict__ s_ptr, const int* __restrict__ l_ptr,
    const int* __restrict__ gcur, const int2* __restrict__ bkt,
    float* __restrict__ out)
{
    __shared__ float tile[256 * DD];    // 64 KB accumulator
    __shared__ float Wp[DD * DD];       // 16 KB W' = theta*W + (1-theta)*I

    int tid = threadIdx.x;
    int b = blockIdx.x;
    float theta = lamda[0] / (float)l_ptr[0];
    float s = s_ptr[0];
    float oms = 1.0f - s;

    float4* t4 = reinterpret_cast<float4*>(tile);
    #pragma unroll
    for (int i = 0; i < 4; ++i) t4[i * 1024 + tid] = make_float4(0.f, 0.f, 0.f, 0.f);
    for (int i = tid; i < DD * DD; i += 1024) {
        int k = i >> 6, j = i & 63;
        float wv = theta * W[i];
        if (k == j) wv += 1.0f - theta;
        Wp[i] = wv;
    }
    int start = (b == 0) ? 0 : gcur[b - 1];
    int end   = gcur[b];
    __syncthreads();

    // accumulate edges: 16 lanes/edge, lane owns columns f4+16k (4-way LDS banks)
    int grp = tid >> 4, f4 = tid & 15;
    for (int e = start + grp; e < end; e += 64) {
        int2 pv = bkt[e];
        int   cc = pv.x & 0xFFFF;
        int   rl = (pv.x >> 16) & 0xFF;
        float vv = __int_as_float(pv.y);
        const float* xr = x + (size_t)cc * DD;
        #pragma unroll
        for (int k = 0; k < 4; ++k) {
            float xv = xr[k * 16 + f4];
            atomicAdd(&tile[rl * DD + k * 16 + f4], vv * xv);
        }
    }
    __syncthreads();

    // mix: tile = (1-s)*tile + s*h0
    const float4* h04 = reinterpret_cast<const float4*>(h0);
    #pragma unroll
    for (int i = 0; i < 4; ++i) {
        int idx = i * 1024 + tid;              // float4 index within tile
        int rl = idx >> 4;
        int r = b * 256 + rl;
        if (r < NN) {
            float4 t = t4[idx];
            float4 h = h04[(size_t)r * 16 + (idx & 15)];
            t.x = oms * t.x + s * h.x;
            t.y = oms * t.y + s * h.y;
            t.z = oms * t.z + s * h.z;
            t.w = oms * t.w + s * h.w;
            t4[idx] = t;
        }
    }
    __syncthreads();

    // GEMM: one wave per row, lane = output column; W' column in registers
    int wave = tid >> 6, lane = tid & 63;
    float w[DD];
    #pragma unroll
    for (int k = 0; k < DD; ++k) w[k] = Wp[k * DD + lane];
    for (int rl = wave; rl < 256; rl += 16) {
        int r = b * 256 + rl;
        if (r >= NN) break;
        float acc = 0.f;
        #pragma unroll
        for (int k = 0; k < DD; ++k)
            acc = fmaf(tile[rl * DD + k], w[k], acc);   // uniform LDS broadcast
        out[(size_t)r * DD + lane] = acc;
    }
}

extern "C" void kernel_launch(void* const* d_in, const int* in_sizes, int n_in,
                              void* d_out, int out_size, void* d_ws, size_t ws_size,
                              hipStream_t stream) {
    const float* x     = (const float*)d_in[0];
    const float* h0    = (const float*)d_in[1];
    const float* evals = (const float*)d_in[2];
    const float* W     = (const float*)d_in[3];
    const int*   erow  = (const int*)d_in[4];
    const int*   ecol  = (const int*)d_in[5];
    const float* lamda = (const float*)d_in[6];
    const float* s_ptr = (const float*)d_in[7];
    const int*   l_ptr = (const int*)d_in[8];
    float* out = (float*)d_out;

    // workspace: 256 cursors + NE int2 bucket array (~12.8 MB)
    char* ws = (char*)d_ws;
    int*  gcur = (int*)ws;
    int2* bkt  = (int2*)(ws + 1024);

    hipMemsetAsync(gcur, 0, 256 * sizeof(int), stream);

    hist_buckets <<<NBLK, 1024, 0, stream>>>(erow, gcur);
    scan_buckets <<<1, 64, 0, stream>>>(gcur);
    bucket_scatter<<<NBLK, 1024, 0, stream>>>(erow, ecol, evals, gcur, bkt);
    fused_spmm_gemm<<<NB, 1024, 0, stream>>>(x, h0, W, lamda, s_ptr, l_ptr,
                                             gcur, bkt, out);
}

// Round 4
// 108.015 us; speedup vs baseline: 7.2920x; 7.2920x over previous
//
#include <hip/hip_runtime.h>

#define NN 50000
#define NE 1600000
#define DD 64
#define RB 128                           // rows per bucket
#define NBK ((NN + RB - 1) / RB)         // 391 buckets
#define BINS 512                         // padded bin count (>= NBK)
#define EPB 4096                         // edges per sort block
#define NBLKA ((NE + EPB - 1) / EPB)     // 391
#define CAP 6144                         // max edges per bucket (mean 4096, sd 64)

// ---------- K1: bucket histogram (LDS-aggregated) ----------
__global__ __launch_bounds__(1024) void hist_buckets(
    const int* __restrict__ erow, int* __restrict__ gcnt)
{
    __shared__ int h[BINS];
    int tid = threadIdx.x;
    if (tid < BINS) h[tid] = 0;
    __syncthreads();
    int base = blockIdx.x * EPB;
    #pragma unroll
    for (int i = 0; i < 4; ++i) {
        int e = base + i * 1024 + tid;
        if (e < NE) atomicAdd(&h[erow[e] >> 7], 1);
    }
    __syncthreads();
    if (tid < BINS) { int c = h[tid]; if (c) atomicAdd(&gcnt[tid], c); }
}

// ---------- K2: exclusive scan of 512 bucket counts, one wave ----------
__global__ __launch_bounds__(64) void scan_buckets(int* __restrict__ gc)
{
    int lane = threadIdx.x;
    int c[8], s = 0;
    #pragma unroll
    for (int i = 0; i < 8; ++i) { c[i] = gc[lane * 8 + i]; s += c[i]; }
    int v = s;
    #pragma unroll
    for (int off = 1; off < 64; off <<= 1) {
        int u = __shfl_up(v, off, 64);
        if (lane >= off) v += u;
    }
    int run = v - s;
    #pragma unroll
    for (int i = 0; i < 8; ++i) { gc[lane * 8 + i] = run; run += c[i]; }
}

// ---------- K3: block-local bucket sort + contiguous-run copy-out ----------
// After this kernel gcur[b] == end offset of bucket b (start = gcur[b-1]).
__global__ __launch_bounds__(1024) void bucket_scatter(
    const int* __restrict__ erow, const int* __restrict__ ecol,
    const float* __restrict__ evals,
    int* __restrict__ gcur, int2* __restrict__ bkt)
{
    __shared__ int hist[BINS];
    __shared__ int lstart[BINS];
    __shared__ int gbase[BINS];
    __shared__ int2 data[EPB];              // 32 KB
    __shared__ unsigned short sbkt[EPB];    // 8 KB

    int tid = threadIdx.x;
    if (tid < BINS) hist[tid] = 0;
    __syncthreads();

    int base = blockIdx.x * EPB;
    int r[4], c[4], bk[4]; float v[4];
    #pragma unroll
    for (int i = 0; i < 4; ++i) {
        int e = base + i * 1024 + tid;
        if (e < NE) {
            r[i] = erow[e]; c[i] = ecol[e]; v[i] = evals[e];
            bk[i] = r[i] >> 7;
            atomicAdd(&hist[bk[i]], 1);
        } else bk[i] = -1;
    }
    __syncthreads();

    if (tid < 64) {                         // wave 0: scan 512 bins, 8/lane
        int cc[8], s = 0;
        #pragma unroll
        for (int i = 0; i < 8; ++i) { cc[i] = hist[tid * 8 + i]; s += cc[i]; }
        int vv = s;
        #pragma unroll
        for (int off = 1; off < 64; off <<= 1) {
            int u = __shfl_up(vv, off, 64);
            if (tid >= off) vv += u;
        }
        int run = vv - s;
        #pragma unroll
        for (int i = 0; i < 8; ++i) { lstart[tid * 8 + i] = run; run += cc[i]; }
    }
    __syncthreads();

    if (tid < BINS) {                       // reserve global runs; hist -> cursor
        int cnt = hist[tid];
        gbase[tid] = cnt ? atomicAdd(&gcur[tid], cnt) : 0;
        hist[tid] = lstart[tid];
    }
    __syncthreads();

    #pragma unroll
    for (int i = 0; i < 4; ++i) {           // scatter into LDS, bucket-grouped
        if (bk[i] >= 0) {
            int p = atomicAdd(&hist[bk[i]], 1);
            data[p] = make_int2(((r[i] & (RB - 1)) << 16) | c[i], __float_as_int(v[i]));
            sbkt[p] = (unsigned short)bk[i];
        }
    }
    __syncthreads();

    int total = NE - base; if (total > EPB) total = EPB;
    #pragma unroll
    for (int i = 0; i < 4; ++i) {           // coalesced copy-out of runs
        int slot = i * 1024 + tid;
        if (slot < total) {
            int bb = sbkt[slot];
            bkt[gbase[bb] + slot - lstart[bb]] = data[slot];
        }
    }
}

// ---------- K4: in-place row sort within each bucket + CSR row_start -------
__global__ __launch_bounds__(1024) void row_sort(
    const int* __restrict__ gcur, int2* __restrict__ bkt,
    int* __restrict__ row_start)
{
    __shared__ int rhist[RB];
    __shared__ int rpre[RB];

    int tid = threadIdx.x;
    int b = blockIdx.x;
    int bstart = (b == 0) ? 0 : gcur[b - 1];
    int bend   = gcur[b];
    int count  = bend - bstart;             // ~4096, hard bound CAP

    if (tid < RB) rhist[tid] = 0;
    __syncthreads();

    int2 ed[CAP / 1024];                    // 6 edges max per thread
    int  rl[CAP / 1024];
    #pragma unroll
    for (int i = 0; i < CAP / 1024; ++i) {
        int idx = i * 1024 + tid;
        if (idx < count) {
            ed[i] = bkt[bstart + idx];
            rl[i] = (ed[i].x >> 16) & (RB - 1);
            atomicAdd(&rhist[rl[i]], 1);
        } else rl[i] = -1;
    }
    __syncthreads();

    if (tid < 64) {                         // scan 128 bins, 2/lane
        int c0 = rhist[tid * 2], c1 = rhist[tid * 2 + 1];
        int s = c0 + c1, vv = s;
        #pragma unroll
        for (int off = 1; off < 64; off <<= 1) {
            int u = __shfl_up(vv, off, 64);
            if (tid >= off) vv += u;
        }
        int run = vv - s;
        rpre[tid * 2] = run;
        rpre[tid * 2 + 1] = run + c0;
    }
    __syncthreads();

    if (tid < RB) {                         // global CSR starts + reset cursors
        int rr = b * RB + tid;
        if (rr < NN) row_start[rr] = bstart + rpre[tid];
        rhist[tid] = rpre[tid];
    }
    if (b == NBK - 1 && tid == RB) row_start[NN] = NE;
    __syncthreads();

    int p[CAP / 1024];
    #pragma unroll
    for (int i = 0; i < CAP / 1024; ++i)
        if (rl[i] >= 0) p[i] = atomicAdd(&rhist[rl[i]], 1);
    __syncthreads();                        // all reads done before any write
    #pragma unroll
    for (int i = 0; i < CAP / 1024; ++i)
        if (rl[i] >= 0) bkt[bstart + p[i]] = ed[i];   // 32KB L2-resident region
}

// ---------- K5: gather SpMM (CSR) + h0 mix + GEMM, no atomics ----------
// out = ((1-s)*A@x + s*h0) @ (theta*W + (1-theta)*I)
__global__ __launch_bounds__(256) void spmm_gemm(
    const float* __restrict__ x,  const float* __restrict__ h0,
    const float* __restrict__ W,  const float* __restrict__ lamda,
    const float* __restrict__ s_ptr, const int* __restrict__ l_ptr,
    const int* __restrict__ row_start, const int2* __restrict__ bkt,
    float* __restrict__ out)
{
    __shared__ float Wp[DD * DD];           // 16 KB W' = theta*W + (1-theta)*I

    float theta = lamda[0] / (float)l_ptr[0];
    float s     = s_ptr[0];

    for (int i = threadIdx.x; i < DD * DD; i += 256) {
        int k = i >> 6, j = i & 63;
        float wv = theta * W[i];
        if (k == j) wv += (1.0f - theta);
        Wp[i] = wv;
    }
    __syncthreads();

    int g  = threadIdx.x >> 4;              // 16 rows per block
    int f4 = threadIdx.x & 15;
    int r  = blockIdx.x * 16 + g;           // grid exact: 50000 = 3125*16

    int start = row_start[r];
    int end   = row_start[r + 1];

    float4 acc = make_float4(0.f, 0.f, 0.f, 0.f);
    int e = start;
    // unroll x4: 4 independent 256B gathers in flight per group
    for (; e + 4 <= end; e += 4) {
        int2 p0 = bkt[e], p1 = bkt[e + 1], p2 = bkt[e + 2], p3 = bkt[e + 3];
        float4 x0 = *reinterpret_cast<const float4*>(x + (size_t)(p0.x & 0xFFFF) * DD + f4 * 4);
        float4 x1 = *reinterpret_cast<const float4*>(x + (size_t)(p1.x & 0xFFFF) * DD + f4 * 4);
        float4 x2 = *reinterpret_cast<const float4*>(x + (size_t)(p2.x & 0xFFFF) * DD + f4 * 4);
        float4 x3 = *reinterpret_cast<const float4*>(x + (size_t)(p3.x & 0xFFFF) * DD + f4 * 4);
        float v0 = __int_as_float(p0.y), v1 = __int_as_float(p1.y);
        float v2 = __int_as_float(p2.y), v3 = __int_as_float(p3.y);
        acc.x = fmaf(v0, x0.x, acc.x); acc.y = fmaf(v0, x0.y, acc.y);
        acc.z = fmaf(v0, x0.z, acc.z); acc.w = fmaf(v0, x0.w, acc.w);
        acc.x = fmaf(v1, x1.x, acc.x); acc.y = fmaf(v1, x1.y, acc.y);
        acc.z = fmaf(v1, x1.z, acc.z); acc.w = fmaf(v1, x1.w, acc.w);
        acc.x = fmaf(v2, x2.x, acc.x); acc.y = fmaf(v2, x2.y, acc.y);
        acc.z = fmaf(v2, x2.z, acc.z); acc.w = fmaf(v2, x2.w, acc.w);
        acc.x = fmaf(v3, x3.x, acc.x); acc.y = fmaf(v3, x3.y, acc.y);
        acc.z = fmaf(v3, x3.z, acc.z); acc.w = fmaf(v3, x3.w, acc.w);
    }
    for (; e < end; ++e) {
        int2 pv = bkt[e];
        float vv = __int_as_float(pv.y);
        float4 xv = *reinterpret_cast<const float4*>(x + (size_t)(pv.x & 0xFFFF) * DD + f4 * 4);
        acc.x = fmaf(vv, xv.x, acc.x); acc.y = fmaf(vv, xv.y, acc.y);
        acc.z = fmaf(vv, xv.z, acc.z); acc.w = fmaf(vv, xv.w, acc.w);
    }

    float4 hb = *reinterpret_cast<const float4*>(h0 + (size_t)r * DD + f4 * 4);
    float oms = 1.0f - s;
    float4 sup;
    sup.x = oms * acc.x + s * hb.x;
    sup.y = oms * acc.y + s * hb.y;
    sup.z = oms * acc.z + s * hb.z;
    sup.w = oms * acc.w + s * hb.w;

    // GEMM row via wave shuffle broadcast of sup[k]
    float4 o = make_float4(0.f, 0.f, 0.f, 0.f);
    int lanebase = threadIdx.x & 48;
    #pragma unroll
    for (int k = 0; k < DD; ++k) {
        float comp = ((k & 3) == 0) ? sup.x :
                     ((k & 3) == 1) ? sup.y :
                     ((k & 3) == 2) ? sup.z : sup.w;
        float sk = __shfl(comp, lanebase + (k >> 2), 64);
        float4 w = *reinterpret_cast<const float4*>(&Wp[k * DD + f4 * 4]);
        o.x = fmaf(sk, w.x, o.x);
        o.y = fmaf(sk, w.y, o.y);
        o.z = fmaf(sk, w.z, o.z);
        o.w = fmaf(sk, w.w, o.w);
    }

    *reinterpret_cast<float4*>(out + (size_t)r * DD + f4 * 4) = o;
}

extern "C" void kernel_launch(void* const* d_in, const int* in_sizes, int n_in,
                              void* d_out, int out_size, void* d_ws, size_t ws_size,
                              hipStream_t stream) {
    const float* x     = (const float*)d_in[0];
    const float* h0    = (const float*)d_in[1];
    const float* evals = (const float*)d_in[2];
    const float* W     = (const float*)d_in[3];
    const int*   erow  = (const int*)d_in[4];
    const int*   ecol  = (const int*)d_in[5];
    const float* lamda = (const float*)d_in[6];
    const float* s_ptr = (const float*)d_in[7];
    const int*   l_ptr = (const int*)d_in[8];
    float* out = (float*)d_out;

    // workspace: gcur[512] | row_start[NN+1] | bkt[NE] int2  (~13.0 MB)
    char* ws = (char*)d_ws;
    int*  gcur      = (int*)ws;
    int*  row_start = (int*)(ws + 2048);
    int2* bkt       = (int2*)(ws + 2048 + (((size_t)(NN + 1) * 4 + 255) & ~(size_t)255));

    hipMemsetAsync(gcur, 0, BINS * sizeof(int), stream);

    hist_buckets  <<<NBLKA, 1024, 0, stream>>>(erow, gcur);
    scan_buckets  <<<1, 64, 0, stream>>>(gcur);
    bucket_scatter<<<NBLKA, 1024, 0, stream>>>(erow, ecol, evals, gcur, bkt);
    row_sort      <<<NBK, 1024, 0, stream>>>(gcur, bkt, row_start);
    spmm_gemm     <<<NN / 16, 256, 0, stream>>>(x, h0, W, lamda, s_ptr, l_ptr,
                                                row_start, bkt, out);
}

// Round 5
// 93.403 us; speedup vs baseline: 8.4327x; 1.1564x over previous
//
#include <hip/hip_runtime.h>

#define NN 50000
#define NE 1600000
#define DD 64
#define RB 128                           // rows per bucket
#define NBK ((NN + RB - 1) / RB)         // 391 buckets
#define BINS 512                         // padded bin count (>= NBK)
#define EPB 4096                         // edges per sort block
#define NBLKA ((NE + EPB - 1) / EPB)     // 391
#define CAP 6144                         // max edges per bucket (mean 4096, sd 64)
#define G4 (NN * DD / 4)                 // 800000 float4 groups in x
#define CONVB 196                        // convert blocks (196*1024*4 >= G4)

__device__ __forceinline__ unsigned short f2bf(float f) {   // RNE
    unsigned u = __float_as_uint(f);
    u += 0x7FFFu + ((u >> 16) & 1u);
    return (unsigned short)(u >> 16);
}

// ---------- K1: bucket histogram (LDS-aggregated) + x->bf16 convert ----------
__global__ __launch_bounds__(1024) void hist_buckets(
    const int* __restrict__ erow, int* __restrict__ gcnt,
    const float* __restrict__ x, uint2* __restrict__ xb /*may be null*/)
{
    int tid = threadIdx.x;
    if (blockIdx.x >= NBLKA) {               // convert blocks
        int t = (blockIdx.x - NBLKA) * 1024 + tid;
        const float4* x4 = reinterpret_cast<const float4*>(x);
        #pragma unroll
        for (int i = 0; i < 4; ++i) {
            int g = i * (CONVB * 1024) + t;
            if (g < G4) {
                float4 v = x4[g];
                uint2 o;
                o.x = (unsigned)f2bf(v.x) | ((unsigned)f2bf(v.y) << 16);
                o.y = (unsigned)f2bf(v.z) | ((unsigned)f2bf(v.w) << 16);
                xb[g] = o;
            }
        }
        return;
    }
    __shared__ int h[BINS];
    if (tid < BINS) h[tid] = 0;
    __syncthreads();
    int base = blockIdx.x * EPB;
    #pragma unroll
    for (int i = 0; i < 4; ++i) {
        int e = base + i * 1024 + tid;
        if (e < NE) atomicAdd(&h[erow[e] >> 7], 1);
    }
    __syncthreads();
    if (tid < BINS) { int c = h[tid]; if (c) atomicAdd(&gcnt[tid], c); }
}

// ---------- K2: exclusive scan of 512 bucket counts, one wave ----------
__global__ __launch_bounds__(64) void scan_buckets(int* __restrict__ gc)
{
    int lane = threadIdx.x;
    int c[8], s = 0;
    #pragma unroll
    for (int i = 0; i < 8; ++i) { c[i] = gc[lane * 8 + i]; s += c[i]; }
    int v = s;
    #pragma unroll
    for (int off = 1; off < 64; off <<= 1) {
        int u = __shfl_up(v, off, 64);
        if (lane >= off) v += u;
    }
    int run = v - s;
    #pragma unroll
    for (int i = 0; i < 8; ++i) { gc[lane * 8 + i] = run; run += c[i]; }
}

// ---------- K3: block-local bucket sort + contiguous-run copy-out ----------
__global__ __launch_bounds__(1024) void bucket_scatter(
    const int* __restrict__ erow, const int* __restrict__ ecol,
    const float* __restrict__ evals,
    int* __restrict__ gcur, int2* __restrict__ bkt)
{
    __shared__ int hist[BINS];
    __shared__ int lstart[BINS];
    __shared__ int gbase[BINS];
    __shared__ int2 data[EPB];              // 32 KB
    __shared__ unsigned short sbkt[EPB];    // 8 KB

    int tid = threadIdx.x;
    if (tid < BINS) hist[tid] = 0;
    __syncthreads();

    int base = blockIdx.x * EPB;
    int r[4], c[4], bk[4]; float v[4];
    #pragma unroll
    for (int i = 0; i < 4; ++i) {
        int e = base + i * 1024 + tid;
        if (e < NE) {
            r[i] = erow[e]; c[i] = ecol[e]; v[i] = evals[e];
            bk[i] = r[i] >> 7;
            atomicAdd(&hist[bk[i]], 1);
        } else bk[i] = -1;
    }
    __syncthreads();

    if (tid < 64) {                         // wave 0: scan 512 bins, 8/lane
        int cc[8], s = 0;
        #pragma unroll
        for (int i = 0; i < 8; ++i) { cc[i] = hist[tid * 8 + i]; s += cc[i]; }
        int vv = s;
        #pragma unroll
        for (int off = 1; off < 64; off <<= 1) {
            int u = __shfl_up(vv, off, 64);
            if (tid >= off) vv += u;
        }
        int run = vv - s;
        #pragma unroll
        for (int i = 0; i < 8; ++i) { lstart[tid * 8 + i] = run; run += cc[i]; }
    }
    __syncthreads();

    if (tid < BINS) {
        int cnt = hist[tid];
        gbase[tid] = cnt ? atomicAdd(&gcur[tid], cnt) : 0;
        hist[tid] = lstart[tid];
    }
    __syncthreads();

    #pragma unroll
    for (int i = 0; i < 4; ++i) {
        if (bk[i] >= 0) {
            int p = atomicAdd(&hist[bk[i]], 1);
            data[p] = make_int2(((r[i] & (RB - 1)) << 16) | c[i], __float_as_int(v[i]));
            sbkt[p] = (unsigned short)bk[i];
        }
    }
    __syncthreads();

    int total = NE - base; if (total > EPB) total = EPB;
    #pragma unroll
    for (int i = 0; i < 4; ++i) {
        int slot = i * 1024 + tid;
        if (slot < total) {
            int bb = sbkt[slot];
            bkt[gbase[bb] + slot - lstart[bb]] = data[slot];
        }
    }
}

// ---------- K4: in-place row sort within each bucket + CSR row_start -------
__global__ __launch_bounds__(1024) void row_sort(
    const int* __restrict__ gcur, int2* __restrict__ bkt,
    int* __restrict__ row_start)
{
    __shared__ int rhist[RB];
    __shared__ int rpre[RB];

    int tid = threadIdx.x;
    int b = blockIdx.x;
    int bstart = (b == 0) ? 0 : gcur[b - 1];
    int bend   = gcur[b];
    int count  = bend - bstart;

    if (tid < RB) rhist[tid] = 0;
    __syncthreads();

    int2 ed[CAP / 1024];
    int  rl[CAP / 1024];
    #pragma unroll
    for (int i = 0; i < CAP / 1024; ++i) {
        int idx = i * 1024 + tid;
        if (idx < count) {
            ed[i] = bkt[bstart + idx];
            rl[i] = (ed[i].x >> 16) & (RB - 1);
            atomicAdd(&rhist[rl[i]], 1);
        } else rl[i] = -1;
    }
    __syncthreads();

    if (tid < 64) {
        int c0 = rhist[tid * 2], c1 = rhist[tid * 2 + 1];
        int s = c0 + c1, vv = s;
        #pragma unroll
        for (int off = 1; off < 64; off <<= 1) {
            int u = __shfl_up(vv, off, 64);
            if (tid >= off) vv += u;
        }
        int run = vv - s;
        rpre[tid * 2] = run;
        rpre[tid * 2 + 1] = run + c0;
    }
    __syncthreads();

    if (tid < RB) {
        int rr = b * RB + tid;
        if (rr < NN) row_start[rr] = bstart + rpre[tid];
        rhist[tid] = rpre[tid];
    }
    if (b == NBK - 1 && tid == RB) row_start[NN] = NE;
    __syncthreads();

    int p[CAP / 1024];
    #pragma unroll
    for (int i = 0; i < CAP / 1024; ++i)
        if (rl[i] >= 0) p[i] = atomicAdd(&rhist[rl[i]], 1);
    __syncthreads();
    #pragma unroll
    for (int i = 0; i < CAP / 1024; ++i)
        if (rl[i] >= 0) bkt[bstart + p[i]] = ed[i];
}

// ---------- K5: gather SpMM (CSR) + h0 mix + GEMM, no atomics ----------
// BF=1: gather bf16 x (half the bytes); accumulate fp32.
template<int BF>
__global__ __launch_bounds__(256) void spmm_gemm(
    const float* __restrict__ x,  const uint2* __restrict__ xb,
    const float* __restrict__ h0,
    const float* __restrict__ W,  const float* __restrict__ lamda,
    const float* __restrict__ s_ptr, const int* __restrict__ l_ptr,
    const int* __restrict__ row_start, const int2* __restrict__ bkt,
    float* __restrict__ out)
{
    __shared__ float Wp[DD * DD];

    float theta = lamda[0] / (float)l_ptr[0];
    float s     = s_ptr[0];

    for (int i = threadIdx.x; i < DD * DD; i += 256) {
        int k = i >> 6, j = i & 63;
        float wv = theta * W[i];
        if (k == j) wv += (1.0f - theta);
        Wp[i] = wv;
    }
    __syncthreads();

    int g  = threadIdx.x >> 4;
    int f4 = threadIdx.x & 15;
    int r  = blockIdx.x * 16 + g;

    int start = row_start[r];
    int end   = row_start[r + 1];

    float4 acc = make_float4(0.f, 0.f, 0.f, 0.f);

    #define GATHER(P, A)                                                        \
        {                                                                       \
            int cc = (P).x & 0xFFFF;                                            \
            float vv = __int_as_float((P).y);                                   \
            if (BF) {                                                           \
                uint2 u = xb[(size_t)cc * 16 + f4];                             \
                (A).x = fmaf(vv, __uint_as_float(u.x << 16), (A).x);            \
                (A).y = fmaf(vv, __uint_as_float(u.x & 0xFFFF0000u), (A).y);    \
                (A).z = fmaf(vv, __uint_as_float(u.y << 16), (A).z);            \
                (A).w = fmaf(vv, __uint_as_float(u.y & 0xFFFF0000u), (A).w);    \
            } else {                                                            \
                float4 xv = *reinterpret_cast<const float4*>(                   \
                    x + (size_t)cc * DD + f4 * 4);                              \
                (A).x = fmaf(vv, xv.x, (A).x);                                  \
                (A).y = fmaf(vv, xv.y, (A).y);                                  \
                (A).z = fmaf(vv, xv.z, (A).z);                                  \
                (A).w = fmaf(vv, xv.w, (A).w);                                  \
            }                                                                   \
        }

    int e = start;
    for (; e + 4 <= end; e += 4) {
        int2 p0 = bkt[e], p1 = bkt[e + 1], p2 = bkt[e + 2], p3 = bkt[e + 3];
        GATHER(p0, acc); GATHER(p1, acc); GATHER(p2, acc); GATHER(p3, acc);
    }
    for (; e < end; ++e) {
        int2 pv = bkt[e];
        GATHER(pv, acc);
    }
    #undef GATHER

    float4 hb = *reinterpret_cast<const float4*>(h0 + (size_t)r * DD + f4 * 4);
    float oms = 1.0f - s;
    float4 sup;
    sup.x = oms * acc.x + s * hb.x;
    sup.y = oms * acc.y + s * hb.y;
    sup.z = oms * acc.z + s * hb.z;
    sup.w = oms * acc.w + s * hb.w;

    float4 o = make_float4(0.f, 0.f, 0.f, 0.f);
    int lanebase = threadIdx.x & 48;
    #pragma unroll
    for (int k = 0; k < DD; ++k) {
        float comp = ((k & 3) == 0) ? sup.x :
                     ((k & 3) == 1) ? sup.y :
                     ((k & 3) == 2) ? sup.z : sup.w;
        float sk = __shfl(comp, lanebase + (k >> 2), 64);
        float4 w = *reinterpret_cast<const float4*>(&Wp[k * DD + f4 * 4]);
        o.x = fmaf(sk, w.x, o.x);
        o.y = fmaf(sk, w.y, o.y);
        o.z = fmaf(sk, w.z, o.z);
        o.w = fmaf(sk, w.w, o.w);
    }

    *reinterpret_cast<float4*>(out + (size_t)r * DD + f4 * 4) = o;
}

extern "C" void kernel_launch(void* const* d_in, const int* in_sizes, int n_in,
                              void* d_out, int out_size, void* d_ws, size_t ws_size,
                              hipStream_t stream) {
    const float* x     = (const float*)d_in[0];
    const float* h0    = (const float*)d_in[1];
    const float* evals = (const float*)d_in[2];
    const float* W     = (const float*)d_in[3];
    const int*   erow  = (const int*)d_in[4];
    const int*   ecol  = (const int*)d_in[5];
    const float* lamda = (const float*)d_in[6];
    const float* s_ptr = (const float*)d_in[7];
    const int*   l_ptr = (const int*)d_in[8];
    float* out = (float*)d_out;

    // workspace: gcur[512] | row_start[NN+1] | bkt[NE] int2 | x_bf[NN*DD] bf16
    char* ws = (char*)d_ws;
    int*   gcur      = (int*)ws;
    int*   row_start = (int*)(ws + 2048);
    size_t bkt_off   = 2048 + (((size_t)(NN + 1) * 4 + 255) & ~(size_t)255);
    int2*  bkt       = (int2*)(ws + bkt_off);
    size_t xb_off    = bkt_off + (size_t)NE * 8;
    uint2* xb        = (uint2*)(ws + xb_off);
    bool use_bf      = (ws_size >= xb_off + (size_t)NN * DD * 2);

    hipMemsetAsync(gcur, 0, BINS * sizeof(int), stream);

    int histgrid = NBLKA + (use_bf ? CONVB : 0);
    hist_buckets  <<<histgrid, 1024, 0, stream>>>(erow, gcur, x, use_bf ? xb : nullptr);
    scan_buckets  <<<1, 64, 0, stream>>>(gcur);
    bucket_scatter<<<NBLKA, 1024, 0, stream>>>(erow, ecol, evals, gcur, bkt);
    row_sort      <<<NBK, 1024, 0, stream>>>(gcur, bkt, row_start);
    if (use_bf)
        spmm_gemm<1><<<NN / 16, 256, 0, stream>>>(x, xb, h0, W, lamda, s_ptr, l_ptr,
                                                  row_start, bkt, out);
    else
        spmm_gemm<0><<<NN / 16, 256, 0, stream>>>(x, xb, h0, W, lamda, s_ptr, l_ptr,
                                                  row_start, bkt, out);
}